// Round 5
// baseline (165.175 us; speedup 1.0000x reference)
//
#include <hip/hip_runtime.h>

typedef __bf16 bf16x8 __attribute__((ext_vector_type(8)));
typedef float f32x16 __attribute__((ext_vector_type(16)));
typedef unsigned short ushort_t;
typedef unsigned int uint_t;

#define S_LEN 2048
#define DH    64
#define NH    64                      // N*H = 8*8 heads
#define KB    64
#define NT    (S_LEN / KB)            // 32 kv tiles
#define QB    128
#define TILE_ELEMS (KB * DH)          // 4096 bf16 per packed tile (8 KB)
#define HEAD_WS    (NT * TILE_ELEMS)  // elems per head per tensor
#define WS_NEEDED  (2ull * NH * HEAD_WS * 2ull)  // bytes

#define QSCALE 0.18033688011112043f   // (1/8) * log2(e)

#if __has_builtin(__builtin_amdgcn_exp2f)
#define EXP2(x) __builtin_amdgcn_exp2f(x)
#else
#define EXP2(x) __expf((x) * 0.6931471805599453f)
#endif

static __device__ __forceinline__ unsigned int f32u(float f) {
  union { float f; unsigned int u; } x; x.f = f; return x.u;
}
// bf16 RNE
static __device__ __forceinline__ ushort_t f2bf(float f) {
  unsigned int u = f32u(f);
  return (ushort_t)((u + 0x7FFFu + ((u >> 16) & 1u)) >> 16);
}

static __device__ __forceinline__ void gl_lds16(const ushort_t* g, ushort_t* l) {
  auto gp = reinterpret_cast<const __attribute__((address_space(1))) char*>(
      reinterpret_cast<uintptr_t>(g));
  auto lp = reinterpret_cast<__attribute__((address_space(3))) char*>(
      (unsigned int)reinterpret_cast<uintptr_t>(l));
  __builtin_amdgcn_global_load_lds(gp, lp, 16, 0, 0);  // dst = lp + lane*16
}

// ---------------- prep: K -> bf16 packed+swizzled, V -> bf16 transposed packed+swizzled ----
// packed tile layout: elem (row, col) at byte  row*128 + (((col>>3) ^ (row&7))<<4) + (col&7)*2
__global__ __launch_bounds__(256) void prep_kv(
    const float* __restrict__ Kg, const float* __restrict__ Vg,
    ushort_t* __restrict__ Kws, ushort_t* __restrict__ Vws) {
  __shared__ float Vl[DH * 65];
  const int tid = threadIdx.x;
  const int tile = blockIdx.x, head = blockIdx.y;
  const size_t gbase = ((size_t)head * S_LEN + (size_t)tile * KB) * DH;
  ushort_t* kdst = Kws + ((size_t)head * NT + tile) * TILE_ELEMS;
  ushort_t* vdst = Vws + ((size_t)head * NT + tile) * TILE_ELEMS;

#pragma unroll
  for (int i = 0; i < 4; ++i) {
    int idx = tid + i * 256;
    int row = idx >> 4;            // kv row
    int c0  = (idx & 15) * 4;      // channel start
    float4 kd = *(const float4*)(Kg + gbase + row * DH + c0);
    float4 vd = *(const float4*)(Vg + gbase + row * DH + c0);
    int chunk = (c0 >> 3) ^ (row & 7);
    ushort4 ko;
    ko.x = f2bf(kd.x); ko.y = f2bf(kd.y); ko.z = f2bf(kd.z); ko.w = f2bf(kd.w);
    *(ushort4*)(kdst + row * 64 + chunk * 8 + (c0 & 7)) = ko;
    Vl[(c0 + 0) * 65 + row] = vd.x;
    Vl[(c0 + 1) * 65 + row] = vd.y;
    Vl[(c0 + 2) * 65 + row] = vd.z;
    Vl[(c0 + 3) * 65 + row] = vd.w;
  }
  __syncthreads();
#pragma unroll
  for (int i = 0; i < 4; ++i) {
    int idx = tid + i * 256;
    int c  = idx >> 4;             // channel row of V^T
    int k0 = (idx & 15) * 4;       // kv start
    int chunk = (k0 >> 3) ^ (c & 7);
    ushort4 vo;
    vo.x = f2bf(Vl[c * 65 + k0 + 0]);
    vo.y = f2bf(Vl[c * 65 + k0 + 1]);
    vo.z = f2bf(Vl[c * 65 + k0 + 2]);
    vo.w = f2bf(Vl[c * 65 + k0 + 3]);
    *(ushort4*)(vdst + c * 64 + chunk * 8 + (k0 & 7)) = vo;
  }
}

// ---------------- main: 32x32 MFMA, swapped operands, 3-deep ring + counted vmcnt ----------
// S^T = K * Q^T  -> lane holds P^T[kv rows][q = lane&31]
// O^T = V^T * P^T -> lane holds O^T[d rows][q = lane&31]
__global__ __launch_bounds__(256, 3) void sdpa_fwd5(
    const float* __restrict__ Qg, const ushort_t* __restrict__ Kws,
    const ushort_t* __restrict__ Vws, float* __restrict__ Og) {
  __shared__ __align__(16) ushort_t Kl[3][TILE_ELEMS];   // 24 KB
  __shared__ __align__(16) ushort_t Vt[3][TILE_ELEMS];   // 24 KB

  const int tid  = threadIdx.x;
  const int w    = tid >> 6;
  const int lane = tid & 63;
  const int hi   = lane >> 5;
  const int l31  = lane & 31;
  const int bid  = blockIdx.x;
  // XCD-affinity: xcd = bid%8 == head%8 -> each XCD's L2 caches 8 heads (4 MB KV)
  const int head  = (bid & 7) | ((bid >> 7) << 3);
  const int qtile = (bid >> 3) & 15;
  const int q0    = qtile * QB;
  const size_t base = (size_t)head * S_LEN * DH;
  const ushort_t* ksrc = Kws + (size_t)head * HEAD_WS;
  const ushort_t* vsrc = Vws + (size_t)head * HEAD_WS;

  // ---- Q B-frags: lane supplies Q[q = l31][c = ks*16 + hi*8 + j], pre-scaled ----
  bf16x8 qf[4];
  {
    const float* qp = Qg + base + (size_t)(q0 + w * 32 + l31) * DH;
#pragma unroll
    for (int ks = 0; ks < 4; ++ks) {
      const float* p = qp + ks * 16 + hi * 8;
      float4 f0 = *(const float4*)p;
      float4 f1 = *(const float4*)(p + 4);
      union { ushort_t u[8]; bf16x8 v; } t;
      t.u[0] = f2bf(f0.x * QSCALE); t.u[1] = f2bf(f0.y * QSCALE);
      t.u[2] = f2bf(f0.z * QSCALE); t.u[3] = f2bf(f0.w * QSCALE);
      t.u[4] = f2bf(f1.x * QSCALE); t.u[5] = f2bf(f1.y * QSCALE);
      t.u[6] = f2bf(f1.z * QSCALE); t.u[7] = f2bf(f1.w * QSCALE);
      qf[ks] = t.v;
    }
  }
  // Drain Q loads so in-loop counted vmcnt sees ONLY staging ops.
  asm volatile("s_waitcnt vmcnt(0)" ::: "memory");

  // ---- per-lane LDS byte offsets (identical formula for K and V^T tiles) ----
  // frag (mt, ks): row = mt*32 + l31, chunk = (ks*2 + hi) ^ (row&7)
  int offs[2][4];
  {
    const int r7 = l31 & 7;
#pragma unroll
    for (int mt = 0; mt < 2; ++mt)
#pragma unroll
      for (int ks = 0; ks < 4; ++ks)
        offs[mt][ks] = (mt * 32 + l31) * 128 + ((((ks << 1) | hi) ^ r7) << 4);
  }

  f32x16 oacc0, oacc1;
#pragma unroll
  for (int r = 0; r < 16; ++r) { oacc0[r] = 0.f; oacc1[r] = 0.f; }
  float lsum = 0.f;

#define STAGE(tt, bb) do { \
    const ushort_t* ks_ = ksrc + (tt) * TILE_ELEMS + w * 512 + lane * 8; \
    const ushort_t* vs_ = vsrc + (tt) * TILE_ELEMS + w * 512 + lane * 8; \
    gl_lds16(ks_,        &Kl[bb][w * 512]); \
    gl_lds16(ks_ + 2048, &Kl[bb][2048 + w * 512]); \
    gl_lds16(vs_,        &Vt[bb][w * 512]); \
    gl_lds16(vs_ + 2048, &Vt[bb][2048 + w * 512]); \
  } while (0)

  // One tile of compute from ring buffer `cur` (literal index).
#define COMPUTE(cur) do { \
    const char* Kc = (const char*)Kl[cur]; \
    const char* Vc = (const char*)Vt[cur]; \
    f32x16 sa0, sa1; \
    _Pragma("unroll") for (int r = 0; r < 16; ++r) { sa0[r] = 0.f; sa1[r] = 0.f; } \
    bf16x8 ka0[4], ka1[4]; \
    _Pragma("unroll") for (int ks = 0; ks < 4; ++ks) { \
      ka0[ks] = *(const bf16x8*)(Kc + offs[0][ks]); \
      ka1[ks] = *(const bf16x8*)(Kc + offs[1][ks]); } \
    __builtin_amdgcn_s_setprio(1); \
    _Pragma("unroll") for (int ks = 0; ks < 4; ++ks) \
      sa0 = __builtin_amdgcn_mfma_f32_32x32x16_bf16(ka0[ks], qf[ks], sa0, 0, 0, 0); \
    _Pragma("unroll") for (int ks = 0; ks < 4; ++ks) \
      sa1 = __builtin_amdgcn_mfma_f32_32x32x16_bf16(ka1[ks], qf[ks], sa1, 0, 0, 0); \
    __builtin_amdgcn_s_setprio(0); \
    union { uint_t u[16]; bf16x8 v[4]; } P; \
    float l0 = 0.f, l1 = 0.f; \
    /* softmax half 0 (sa0) -> P.u[0..7]; overlaps sa1's MFMAs */ \
    _Pragma("unroll") for (int i = 0; i < 8; ++i) { \
      float a = EXP2(sa0[2 * i]), b = EXP2(sa0[2 * i + 1]); \
      l0 += a + b; \
      asm("v_cvt_pk_bf16_f32 %0, %1, %2" : "=v"(P.u[i]) : "v"(a), "v"(b)); } \
    asm("v_permlane32_swap_b32 %0, %1" : "+v"(P.u[0]), "+v"(P.u[2])); \
    asm("v_permlane32_swap_b32 %0, %1" : "+v"(P.u[1]), "+v"(P.u[3])); \
    asm("v_permlane32_swap_b32 %0, %1" : "+v"(P.u[4]), "+v"(P.u[6])); \
    asm("v_permlane32_swap_b32 %0, %1" : "+v"(P.u[5]), "+v"(P.u[7])); \
    /* PV slots 0,1 (kv 0..31); exp2(sa1) below overlaps these MFMAs */ \
    __builtin_amdgcn_s_setprio(1); \
    { bf16x8 vv; \
      vv = *(const bf16x8*)(Vc + offs[0][0]); \
      oacc0 = __builtin_amdgcn_mfma_f32_32x32x16_bf16(vv, P.v[0], oacc0, 0, 0, 0); \
      vv = *(const bf16x8*)(Vc + offs[1][0]); \
      oacc1 = __builtin_amdgcn_mfma_f32_32x32x16_bf16(vv, P.v[0], oacc1, 0, 0, 0); \
      vv = *(const bf16x8*)(Vc + offs[0][1]); \
      oacc0 = __builtin_amdgcn_mfma_f32_32x32x16_bf16(vv, P.v[1], oacc0, 0, 0, 0); \
      vv = *(const bf16x8*)(Vc + offs[1][1]); \
      oacc1 = __builtin_amdgcn_mfma_f32_32x32x16_bf16(vv, P.v[1], oacc1, 0, 0, 0); } \
    __builtin_amdgcn_s_setprio(0); \
    /* softmax half 1 (sa1) -> P.u[8..15] */ \
    _Pragma("unroll") for (int i = 0; i < 8; ++i) { \
      float a = EXP2(sa1[2 * i]), b = EXP2(sa1[2 * i + 1]); \
      l1 += a + b; \
      asm("v_cvt_pk_bf16_f32 %0, %1, %2" : "=v"(P.u[i + 8]) : "v"(a), "v"(b)); } \
    asm("v_permlane32_swap_b32 %0, %1" : "+v"(P.u[8]),  "+v"(P.u[10])); \
    asm("v_permlane32_swap_b32 %0, %1" : "+v"(P.u[9]),  "+v"(P.u[11])); \
    asm("v_permlane32_swap_b32 %0, %1" : "+v"(P.u[12]), "+v"(P.u[14])); \
    asm("v_permlane32_swap_b32 %0, %1" : "+v"(P.u[13]), "+v"(P.u[15])); \
    /* PV slots 2,3 (kv 32..63) */ \
    __builtin_amdgcn_s_setprio(1); \
    { bf16x8 vv; \
      vv = *(const bf16x8*)(Vc + offs[0][2]); \
      oacc0 = __builtin_amdgcn_mfma_f32_32x32x16_bf16(vv, P.v[2], oacc0, 0, 0, 0); \
      vv = *(const bf16x8*)(Vc + offs[1][2]); \
      oacc1 = __builtin_amdgcn_mfma_f32_32x32x16_bf16(vv, P.v[2], oacc1, 0, 0, 0); \
      vv = *(const bf16x8*)(Vc + offs[0][3]); \
      oacc0 = __builtin_amdgcn_mfma_f32_32x32x16_bf16(vv, P.v[3], oacc0, 0, 0, 0); \
      vv = *(const bf16x8*)(Vc + offs[1][3]); \
      oacc1 = __builtin_amdgcn_mfma_f32_32x32x16_bf16(vv, P.v[3], oacc1, 0, 0, 0); } \
    __builtin_amdgcn_s_setprio(0); \
    lsum += l0 + l1; \
  } while (0)

#define WAITN(n) asm volatile("s_waitcnt vmcnt(" #n ")" ::: "memory")
#define BARRIER() do { \
    __builtin_amdgcn_sched_barrier(0); \
    __builtin_amdgcn_s_barrier(); \
    __builtin_amdgcn_sched_barrier(0); \
  } while (0)

  // prologue: stage tiles 0,1 (8 loads/wave in flight)
  STAGE(0, 0);
  STAGE(1, 1);

  // main loop: iter t = {wait tile-t loads (keep t+1 in flight), barrier,
  //                      stage t+2 into (t+2)%3, compute t}.  NT=32 -> t=0..29.
#pragma unroll 1
  for (int tb = 0; tb < NT - 2; tb += 3) {
    WAITN(4); BARRIER(); STAGE(tb + 2, 2); COMPUTE(0);
    WAITN(4); BARRIER(); STAGE(tb + 3, 0); COMPUTE(1);
    WAITN(4); BARRIER(); STAGE(tb + 4, 1); COMPUTE(2);
  }
  // peel t = 30 (buf 0), t = 31 (buf 1); no more staging
  WAITN(4); BARRIER(); COMPUTE(0);
  WAITN(0); BARRIER(); COMPUTE(1);

#undef STAGE
#undef COMPUTE
#undef WAITN
#undef BARRIER

  // ---- epilogue: l is lane-local (q = l31); O^T regs -> row-major O with float4 ----
  float ltot = lsum + __shfl_xor(lsum, 32);
  float linv = 1.0f / ltot;
  float* orow = Og + base + (size_t)(q0 + w * 32 + l31) * DH;
#pragma unroll
  for (int rr = 0; rr < 4; ++rr) {
    float4 o0, o1;
    o0.x = oacc0[4 * rr + 0] * linv; o0.y = oacc0[4 * rr + 1] * linv;
    o0.z = oacc0[4 * rr + 2] * linv; o0.w = oacc0[4 * rr + 3] * linv;
    o1.x = oacc1[4 * rr + 0] * linv; o1.y = oacc1[4 * rr + 1] * linv;
    o1.z = oacc1[4 * rr + 2] * linv; o1.w = oacc1[4 * rr + 3] * linv;
    *(float4*)(orow + 8 * rr + 4 * hi) = o0;          // d = 0..31 tile
    *(float4*)(orow + 32 + 8 * rr + 4 * hi) = o1;     // d = 32..63 tile
  }
}

// ---------------- fallback (used only if ws too small): self-contained fp32->bf16 ----
#define LSTR 72
__global__ __launch_bounds__(256) void sdpa_fwd_v1(
    const float* __restrict__ Qg, const float* __restrict__ Kg,
    const float* __restrict__ Vg, float* __restrict__ Og) {
  __shared__ __align__(16) ushort_t Klv[KB * LSTR];
  __shared__ __align__(16) ushort_t Vtv[DH * LSTR];
  __shared__ __align__(16) ushort_t Plv[4 * 16 * LSTR];
  typedef float f32x4s __attribute__((ext_vector_type(4)));
  const int tid = threadIdx.x;
  const int w = tid >> 6, lane = tid & 63, lg = lane >> 4, li = lane & 15;
  const int bh = blockIdx.y;
  const int q0 = blockIdx.x * 64;
  const size_t base = (size_t)bh * S_LEN * DH;
  bf16x8 aq[2];
  {
    const float* qrow = Qg + base + (size_t)(q0 + w * 16 + li) * DH;
    for (int s = 0; s < 2; ++s) {
      union { ushort_t u[8]; bf16x8 v; } t;
      const float* p = qrow + s * 32 + lg * 8;
      float4 f0 = *(const float4*)(p);
      float4 f1 = *(const float4*)(p + 4);
      t.u[0] = f2bf(f0.x * 0.125f); t.u[1] = f2bf(f0.y * 0.125f);
      t.u[2] = f2bf(f0.z * 0.125f); t.u[3] = f2bf(f0.w * 0.125f);
      t.u[4] = f2bf(f1.x * 0.125f); t.u[5] = f2bf(f1.y * 0.125f);
      t.u[6] = f2bf(f1.z * 0.125f); t.u[7] = f2bf(f1.w * 0.125f);
      aq[s] = t.v;
    }
  }
  f32x4s oacc[4]; float mrow[4], lrow[4];
  for (int n = 0; n < 4; ++n) oacc[n] = (f32x4s){0.f, 0.f, 0.f, 0.f};
  for (int r = 0; r < 4; ++r) { mrow[r] = -1e30f; lrow[r] = 0.f; }
  ushort_t* Pw = &Plv[w * 16 * LSTR];
  for (int kv0 = 0; kv0 < S_LEN; kv0 += KB) {
    __syncthreads();
    for (int i = 0; i < 4; ++i) {
      int f4 = tid + i * 256;
      int row = f4 >> 4, c0 = (f4 & 15) * 4;
      size_t goff = base + (size_t)(kv0 + row) * DH + c0;
      float4 kd = *(const float4*)(Kg + goff);
      float4 vd = *(const float4*)(Vg + goff);
      ushort_t* kp = &Klv[row * LSTR + c0];
      kp[0] = f2bf(kd.x); kp[1] = f2bf(kd.y); kp[2] = f2bf(kd.z); kp[3] = f2bf(kd.w);
      Vtv[(c0 + 0) * LSTR + row] = f2bf(vd.x);
      Vtv[(c0 + 1) * LSTR + row] = f2bf(vd.y);
      Vtv[(c0 + 2) * LSTR + row] = f2bf(vd.z);
      Vtv[(c0 + 3) * LSTR + row] = f2bf(vd.w);
    }
    __syncthreads();
    f32x4s sa[4];
    for (int n = 0; n < 4; ++n) sa[n] = (f32x4s){0.f, 0.f, 0.f, 0.f};
    for (int n = 0; n < 4; ++n)
      for (int s = 0; s < 2; ++s) {
        bf16x8 bk = *(const bf16x8*)&Klv[(n * 16 + li) * LSTR + s * 32 + lg * 8];
        sa[n] = __builtin_amdgcn_mfma_f32_16x16x32_bf16(aq[s], bk, sa[n], 0, 0, 0);
      }
    float mt[4];
    for (int r = 0; r < 4; ++r)
      mt[r] = fmaxf(fmaxf(sa[0][r], sa[1][r]), fmaxf(sa[2][r], sa[3][r]));
    for (int mask = 1; mask < 16; mask <<= 1)
      for (int r = 0; r < 4; ++r) mt[r] = fmaxf(mt[r], __shfl_xor(mt[r], mask));
    float alpha[4];
    for (int r = 0; r < 4; ++r) {
      float mn = fmaxf(mrow[r], mt[r]);
      alpha[r] = __expf(mrow[r] - mn);
      mrow[r] = mn;
    }
    float p[4][4], ps[4];
    for (int n = 0; n < 4; ++n)
      for (int r = 0; r < 4; ++r) p[n][r] = __expf(sa[n][r] - mrow[r]);
    for (int r = 0; r < 4; ++r) ps[r] = (p[0][r] + p[1][r]) + (p[2][r] + p[3][r]);
    for (int mask = 1; mask < 16; mask <<= 1)
      for (int r = 0; r < 4; ++r) ps[r] += __shfl_xor(ps[r], mask);
    for (int r = 0; r < 4; ++r) lrow[r] = lrow[r] * alpha[r] + ps[r];
    for (int n = 0; n < 4; ++n)
      for (int r = 0; r < 4; ++r) oacc[n][r] *= alpha[r];
    for (int n = 0; n < 4; ++n)
      for (int r = 0; r < 4; ++r)
        Pw[(lg * 4 + r) * LSTR + n * 16 + li] = f2bf(p[n][r]);
    bf16x8 ap[2];
    for (int s = 0; s < 2; ++s)
      ap[s] = *(const bf16x8*)&Pw[li * LSTR + s * 32 + lg * 8];
    for (int n = 0; n < 4; ++n)
      for (int s = 0; s < 2; ++s) {
        bf16x8 bv = *(const bf16x8*)&Vtv[(n * 16 + li) * LSTR + s * 32 + lg * 8];
        oacc[n] = __builtin_amdgcn_mfma_f32_16x16x32_bf16(ap[s], bv, oacc[n], 0, 0, 0);
      }
  }
  for (int r = 0; r < 4; ++r) {
    float inv = 1.0f / lrow[r];
    size_t rowoff = base + (size_t)(q0 + w * 16 + lg * 4 + r) * DH;
    for (int n = 0; n < 4; ++n) Og[rowoff + n * 16 + li] = oacc[n][r] * inv;
  }
}

extern "C" void kernel_launch(void* const* d_in, const int* in_sizes, int n_in,
                              void* d_out, int out_size, void* d_ws, size_t ws_size,
                              hipStream_t stream) {
  const float* Qg = (const float*)d_in[0];
  const float* Kg = (const float*)d_in[1];
  const float* Vg = (const float*)d_in[2];
  float* Og = (float*)d_out;
  if (ws_size >= WS_NEEDED) {
    ushort_t* Kws = (ushort_t*)d_ws;
    ushort_t* Vws = Kws + (size_t)NH * HEAD_WS;
    prep_kv<<<dim3(NT, NH), 256, 0, stream>>>(Kg, Vg, Kws, Vws);
    sdpa_fwd5<<<dim3(1024), 256, 0, stream>>>(Qg, Kws, Vws, Og);
  } else {
    sdpa_fwd_v1<<<dim3(S_LEN / 64, NH), 256, 0, stream>>>(Qg, Kg, Vg, Og);
  }
}

// Round 6
// 113.374 us; speedup vs baseline: 1.4569x; 1.4569x over previous
//
#include <hip/hip_runtime.h>

typedef __bf16 bf16x8 __attribute__((ext_vector_type(8)));
typedef float f32x16 __attribute__((ext_vector_type(16)));
typedef float f32x2 __attribute__((ext_vector_type(2)));
typedef unsigned short ushort_t;
typedef unsigned int uint_t;

#define S_LEN 2048
#define DH    64
#define NH    64                      // N*H = 8*8 heads
#define KB    64
#define NT    (S_LEN / KB)            // 32 kv tiles
#define QB    128
#define TILE_ELEMS (KB * DH)          // 4096 bf16 per packed tile (8 KB)
#define TILE_BYTES (TILE_ELEMS * 2)
#define HEAD_WS    (NT * TILE_ELEMS)  // elems per head per tensor
#define WS_NEEDED  (2ull * NH * HEAD_WS * 2ull)  // bytes

#define QSCALE 0.18033688011112043f   // (1/8) * log2(e)

#if __has_builtin(__builtin_amdgcn_exp2f)
#define EXP2(x) __builtin_amdgcn_exp2f(x)
#else
#define EXP2(x) __expf((x) * 0.6931471805599453f)
#endif

static __device__ __forceinline__ unsigned int f32u(float f) {
  union { float f; unsigned int u; } x; x.f = f; return x.u;
}
// bf16 RNE
static __device__ __forceinline__ ushort_t f2bf(float f) {
  unsigned int u = f32u(f);
  return (ushort_t)((u + 0x7FFFu + ((u >> 16) & 1u)) >> 16);
}

static __device__ __forceinline__ void gl_lds16(const ushort_t* g, ushort_t* l) {
  auto gp = reinterpret_cast<const __attribute__((address_space(1))) char*>(
      reinterpret_cast<uintptr_t>(g));
  auto lp = reinterpret_cast<__attribute__((address_space(3))) char*>(
      (unsigned int)reinterpret_cast<uintptr_t>(l));
  __builtin_amdgcn_global_load_lds(gp, lp, 16, 0, 0);  // dst = lp + lane*16
}

// ---------------- prep: K -> bf16 packed+swizzled, V -> bf16 transposed packed+swizzled ----
// packed tile layout: elem (row, col) at byte  row*128 + (((col>>3) ^ (row&7))<<4) + (col&7)*2
__global__ __launch_bounds__(256) void prep_kv(
    const float* __restrict__ Kg, const float* __restrict__ Vg,
    ushort_t* __restrict__ Kws, ushort_t* __restrict__ Vws) {
  __shared__ float Vl[DH * 65];
  const int tid = threadIdx.x;
  const int tile = blockIdx.x, head = blockIdx.y;
  const size_t gbase = ((size_t)head * S_LEN + (size_t)tile * KB) * DH;
  ushort_t* kdst = Kws + ((size_t)head * NT + tile) * TILE_ELEMS;
  ushort_t* vdst = Vws + ((size_t)head * NT + tile) * TILE_ELEMS;

#pragma unroll
  for (int i = 0; i < 4; ++i) {
    int idx = tid + i * 256;
    int row = idx >> 4;            // kv row
    int c0  = (idx & 15) * 4;      // channel start
    float4 kd = *(const float4*)(Kg + gbase + row * DH + c0);
    float4 vd = *(const float4*)(Vg + gbase + row * DH + c0);
    int chunk = (c0 >> 3) ^ (row & 7);
    ushort4 ko;
    ko.x = f2bf(kd.x); ko.y = f2bf(kd.y); ko.z = f2bf(kd.z); ko.w = f2bf(kd.w);
    *(ushort4*)(kdst + row * 64 + chunk * 8 + (c0 & 7)) = ko;
    Vl[(c0 + 0) * 65 + row] = vd.x;
    Vl[(c0 + 1) * 65 + row] = vd.y;
    Vl[(c0 + 2) * 65 + row] = vd.z;
    Vl[(c0 + 3) * 65 + row] = vd.w;
  }
  __syncthreads();
#pragma unroll
  for (int i = 0; i < 4; ++i) {
    int idx = tid + i * 256;
    int c  = idx >> 4;             // channel row of V^T
    int k0 = (idx & 15) * 4;       // kv start
    int chunk = (k0 >> 3) ^ (c & 7);
    ushort4 vo;
    vo.x = f2bf(Vl[c * 65 + k0 + 0]);
    vo.y = f2bf(Vl[c * 65 + k0 + 1]);
    vo.z = f2bf(Vl[c * 65 + k0 + 2]);
    vo.w = f2bf(Vl[c * 65 + k0 + 3]);
    *(ushort4*)(vdst + c * 64 + chunk * 8 + (k0 & 7)) = vo;
  }
}

// ---------------- main: 32x32 MFMA, swapped operands, ring-3 + counted vmcnt (rolled) ------
// S^T = K * Q^T  -> lane holds P^T[kv rows][q = lane&31]
// O^T = V^T * P^T -> lane holds O^T[d rows][q = lane&31]
__global__ __launch_bounds__(256) void sdpa_fwd6(
    const float* __restrict__ Qg, const ushort_t* __restrict__ Kws,
    const ushort_t* __restrict__ Vws, float* __restrict__ Og) {
  __shared__ __align__(16) ushort_t Kl[3][TILE_ELEMS];   // 24 KB
  __shared__ __align__(16) ushort_t Vt[3][TILE_ELEMS];   // 24 KB

  const int tid  = threadIdx.x;
  const int w    = tid >> 6;
  const int lane = tid & 63;
  const int hi   = lane >> 5;
  const int l31  = lane & 31;
  const int bid  = blockIdx.x;
  // XCD-affinity: xcd = bid%8 == head%8 -> each XCD's L2 caches 8 heads (4 MB KV)
  const int head  = (bid & 7) | ((bid >> 7) << 3);
  const int qtile = (bid >> 3) & 15;
  const int q0    = qtile * QB;
  const size_t base = (size_t)head * S_LEN * DH;
  const ushort_t* ksrc = Kws + (size_t)head * HEAD_WS;
  const ushort_t* vsrc = Vws + (size_t)head * HEAD_WS;

  // ---- Q B-frags: lane supplies Q[q = l31][c = ks*16 + hi*8 + j], pre-scaled ----
  bf16x8 qf[4];
  {
    const float* qp = Qg + base + (size_t)(q0 + w * 32 + l31) * DH;
#pragma unroll
    for (int ks = 0; ks < 4; ++ks) {
      const float* p = qp + ks * 16 + hi * 8;
      float4 f0 = *(const float4*)p;
      float4 f1 = *(const float4*)(p + 4);
      union { ushort_t u[8]; bf16x8 v; } t;
      t.u[0] = f2bf(f0.x * QSCALE); t.u[1] = f2bf(f0.y * QSCALE);
      t.u[2] = f2bf(f0.z * QSCALE); t.u[3] = f2bf(f0.w * QSCALE);
      t.u[4] = f2bf(f1.x * QSCALE); t.u[5] = f2bf(f1.y * QSCALE);
      t.u[6] = f2bf(f1.z * QSCALE); t.u[7] = f2bf(f1.w * QSCALE);
      qf[ks] = t.v;
    }
  }
  // Drain Q loads so in-loop counted vmcnt sees ONLY staging DMA ops.
  asm volatile("s_waitcnt vmcnt(0)" ::: "memory");

  // ---- per-lane LDS byte offsets (identical formula for K and V^T tiles) ----
  // frag (mt, ks): row = mt*32 + l31, chunk = (ks*2 + hi) ^ (row&7)
  int offs[2][4];
  {
    const int r7 = l31 & 7;
#pragma unroll
    for (int mt = 0; mt < 2; ++mt)
#pragma unroll
      for (int ks = 0; ks < 4; ++ks)
        offs[mt][ks] = (mt * 32 + l31) * 128 + ((((ks << 1) | hi) ^ r7) << 4);
  }

  f32x16 oacc0, oacc1;
#pragma unroll
  for (int r = 0; r < 16; ++r) { oacc0[r] = 0.f; oacc1[r] = 0.f; }
  f32x2 ls0 = {0.f, 0.f}, ls1 = {0.f, 0.f};

#define STAGE(tt, bb) do { \
    const ushort_t* ks_ = ksrc + (tt) * TILE_ELEMS + w * 512 + lane * 8; \
    const ushort_t* vs_ = vsrc + (tt) * TILE_ELEMS + w * 512 + lane * 8; \
    gl_lds16(ks_,        &Kl[bb][w * 512]); \
    gl_lds16(ks_ + 2048, &Kl[bb][2048 + w * 512]); \
    gl_lds16(vs_,        &Vt[bb][w * 512]); \
    gl_lds16(vs_ + 2048, &Vt[bb][2048 + w * 512]); \
  } while (0)

  // prologue: stage tiles 0,1 (8 DMA ops/wave in flight)
  STAGE(0, 0);
  STAGE(1, 1);

  int cur = 0, nxt = 2;
#pragma unroll 1
  for (int t = 0; t < NT; ++t) {
    // own DMA for tile t done (t+1's 4 ops stay in flight); tail drains fully
    if (t < NT - 1) asm volatile("s_waitcnt vmcnt(4)" ::: "memory");
    else            asm volatile("s_waitcnt vmcnt(0)" ::: "memory");
    // all waves: tile-t DMA visible AND done reading buf (t-1)%3 == nxt
    __builtin_amdgcn_s_barrier();
    if (t + 2 < NT) STAGE(t + 2, nxt);

    const char* Kc = (const char*)Kl + cur * TILE_BYTES;
    const char* Vc = (const char*)Vt + cur * TILE_BYTES;

    // ---- S^T = K Q^T : two 32(kv) x 32(q) tiles ----
    f32x16 sa0, sa1;
#pragma unroll
    for (int r = 0; r < 16; ++r) { sa0[r] = 0.f; sa1[r] = 0.f; }
    bf16x8 ka0[4], ka1[4];
#pragma unroll
    for (int ks = 0; ks < 4; ++ks) {
      ka0[ks] = *(const bf16x8*)(Kc + offs[0][ks]);
      ka1[ks] = *(const bf16x8*)(Kc + offs[1][ks]);
    }
    __builtin_amdgcn_s_setprio(1);
#pragma unroll
    for (int ks = 0; ks < 4; ++ks) {
      sa0 = __builtin_amdgcn_mfma_f32_32x32x16_bf16(ka0[ks], qf[ks], sa0, 0, 0, 0);
      sa1 = __builtin_amdgcn_mfma_f32_32x32x16_bf16(ka1[ks], qf[ks], sa1, 0, 0, 0);
    }
    __builtin_amdgcn_s_setprio(0);

    // ---- p = exp2(S^T); cvt_pk to bf16 pairs; permlane32_swap -> PV B-frags ----
    union { uint_t u[16]; bf16x8 v[4]; } P;
#pragma unroll
    for (int i = 0; i < 8; ++i) {
      float a = EXP2(sa0[2 * i]), b = EXP2(sa0[2 * i + 1]);
      ls0 += (f32x2){a, b};
      asm("v_cvt_pk_bf16_f32 %0, %1, %2" : "=v"(P.u[i]) : "v"(a), "v"(b));
    }
#pragma unroll
    for (int i = 0; i < 8; ++i) {
      float a = EXP2(sa1[2 * i]), b = EXP2(sa1[2 * i + 1]);
      ls1 += (f32x2){a, b};
      asm("v_cvt_pk_bf16_f32 %0, %1, %2" : "=v"(P.u[i + 8]) : "v"(a), "v"(b));
    }
#pragma unroll
    for (int g = 0; g < 4; ++g) {
      asm("v_permlane32_swap_b32 %0, %1" : "+v"(P.u[4 * g + 0]), "+v"(P.u[4 * g + 2]));
      asm("v_permlane32_swap_b32 %0, %1" : "+v"(P.u[4 * g + 1]), "+v"(P.u[4 * g + 3]));
    }

    // ---- O^T += V^T P^T : two 32(d) x 32(q) tiles, 4 k-slots of 16 kv ----
    __builtin_amdgcn_s_setprio(1);
    {
      bf16x8 vv;
      vv = *(const bf16x8*)(Vc + offs[0][0]);
      oacc0 = __builtin_amdgcn_mfma_f32_32x32x16_bf16(vv, P.v[0], oacc0, 0, 0, 0);
      vv = *(const bf16x8*)(Vc + offs[1][0]);
      oacc1 = __builtin_amdgcn_mfma_f32_32x32x16_bf16(vv, P.v[0], oacc1, 0, 0, 0);
      vv = *(const bf16x8*)(Vc + offs[0][1]);
      oacc0 = __builtin_amdgcn_mfma_f32_32x32x16_bf16(vv, P.v[1], oacc0, 0, 0, 0);
      vv = *(const bf16x8*)(Vc + offs[1][1]);
      oacc1 = __builtin_amdgcn_mfma_f32_32x32x16_bf16(vv, P.v[1], oacc1, 0, 0, 0);
      vv = *(const bf16x8*)(Vc + offs[0][2]);
      oacc0 = __builtin_amdgcn_mfma_f32_32x32x16_bf16(vv, P.v[2], oacc0, 0, 0, 0);
      vv = *(const bf16x8*)(Vc + offs[1][2]);
      oacc1 = __builtin_amdgcn_mfma_f32_32x32x16_bf16(vv, P.v[2], oacc1, 0, 0, 0);
      vv = *(const bf16x8*)(Vc + offs[0][3]);
      oacc0 = __builtin_amdgcn_mfma_f32_32x32x16_bf16(vv, P.v[3], oacc0, 0, 0, 0);
      vv = *(const bf16x8*)(Vc + offs[1][3]);
      oacc1 = __builtin_amdgcn_mfma_f32_32x32x16_bf16(vv, P.v[3], oacc1, 0, 0, 0);
    }
    __builtin_amdgcn_s_setprio(0);

    cur = (cur == 2) ? 0 : cur + 1;
    nxt = (nxt == 2) ? 0 : nxt + 1;
  }
#undef STAGE

  // ---- epilogue: l is lane-local (q = l31); O^T regs -> row-major O with float4 ----
  float lsum = ls0.x + ls0.y + ls1.x + ls1.y;
  float ltot = lsum + __shfl_xor(lsum, 32);
  float linv = 1.0f / ltot;
  float* orow = Og + base + (size_t)(q0 + w * 32 + l31) * DH;
#pragma unroll
  for (int rr = 0; rr < 4; ++rr) {
    float4 o0, o1;
    o0.x = oacc0[4 * rr + 0] * linv; o0.y = oacc0[4 * rr + 1] * linv;
    o0.z = oacc0[4 * rr + 2] * linv; o0.w = oacc0[4 * rr + 3] * linv;
    o1.x = oacc1[4 * rr + 0] * linv; o1.y = oacc1[4 * rr + 1] * linv;
    o1.z = oacc1[4 * rr + 2] * linv; o1.w = oacc1[4 * rr + 3] * linv;
    *(float4*)(orow + 8 * rr + 4 * hi) = o0;          // d = 0..31 tile
    *(float4*)(orow + 32 + 8 * rr + 4 * hi) = o1;     // d = 32..63 tile
  }
}

// ---------------- fallback (used only if ws too small): self-contained fp32->bf16 ----
#define LSTR 72
__global__ __launch_bounds__(256) void sdpa_fwd_v1(
    const float* __restrict__ Qg, const float* __restrict__ Kg,
    const float* __restrict__ Vg, float* __restrict__ Og) {
  __shared__ __align__(16) ushort_t Klv[KB * LSTR];
  __shared__ __align__(16) ushort_t Vtv[DH * LSTR];
  __shared__ __align__(16) ushort_t Plv[4 * 16 * LSTR];
  typedef float f32x4s __attribute__((ext_vector_type(4)));
  const int tid = threadIdx.x;
  const int w = tid >> 6, lane = tid & 63, lg = lane >> 4, li = lane & 15;
  const int bh = blockIdx.y;
  const int q0 = blockIdx.x * 64;
  const size_t base = (size_t)bh * S_LEN * DH;
  bf16x8 aq[2];
  {
    const float* qrow = Qg + base + (size_t)(q0 + w * 16 + li) * DH;
    for (int s = 0; s < 2; ++s) {
      union { ushort_t u[8]; bf16x8 v; } t;
      const float* p = qrow + s * 32 + lg * 8;
      float4 f0 = *(const float4*)(p);
      float4 f1 = *(const float4*)(p + 4);
      t.u[0] = f2bf(f0.x * 0.125f); t.u[1] = f2bf(f0.y * 0.125f);
      t.u[2] = f2bf(f0.z * 0.125f); t.u[3] = f2bf(f0.w * 0.125f);
      t.u[4] = f2bf(f1.x * 0.125f); t.u[5] = f2bf(f1.y * 0.125f);
      t.u[6] = f2bf(f1.z * 0.125f); t.u[7] = f2bf(f1.w * 0.125f);
      aq[s] = t.v;
    }
  }
  f32x4s oacc[4]; float mrow[4], lrow[4];
  for (int n = 0; n < 4; ++n) oacc[n] = (f32x4s){0.f, 0.f, 0.f, 0.f};
  for (int r = 0; r < 4; ++r) { mrow[r] = -1e30f; lrow[r] = 0.f; }
  ushort_t* Pw = &Plv[w * 16 * LSTR];
  for (int kv0 = 0; kv0 < S_LEN; kv0 += KB) {
    __syncthreads();
    for (int i = 0; i < 4; ++i) {
      int f4 = tid + i * 256;
      int row = f4 >> 4, c0 = (f4 & 15) * 4;
      size_t goff = base + (size_t)(kv0 + row) * DH + c0;
      float4 kd = *(const float4*)(Kg + goff);
      float4 vd = *(const float4*)(Vg + goff);
      ushort_t* kp = &Klv[row * LSTR + c0];
      kp[0] = f2bf(kd.x); kp[1] = f2bf(kd.y); kp[2] = f2bf(kd.z); kp[3] = f2bf(kd.w);
      Vtv[(c0 + 0) * LSTR + row] = f2bf(vd.x);
      Vtv[(c0 + 1) * LSTR + row] = f2bf(vd.y);
      Vtv[(c0 + 2) * LSTR + row] = f2bf(vd.z);
      Vtv[(c0 + 3) * LSTR + row] = f2bf(vd.w);
    }
    __syncthreads();
    f32x4s sa[4];
    for (int n = 0; n < 4; ++n) sa[n] = (f32x4s){0.f, 0.f, 0.f, 0.f};
    for (int n = 0; n < 4; ++n)
      for (int s = 0; s < 2; ++s) {
        bf16x8 bk = *(const bf16x8*)&Klv[(n * 16 + li) * LSTR + s * 32 + lg * 8];
        sa[n] = __builtin_amdgcn_mfma_f32_16x16x32_bf16(aq[s], bk, sa[n], 0, 0, 0);
      }
    float mt[4];
    for (int r = 0; r < 4; ++r)
      mt[r] = fmaxf(fmaxf(sa[0][r], sa[1][r]), fmaxf(sa[2][r], sa[3][r]));
    for (int mask = 1; mask < 16; mask <<= 1)
      for (int r = 0; r < 4; ++r) mt[r] = fmaxf(mt[r], __shfl_xor(mt[r], mask));
    float alpha[4];
    for (int r = 0; r < 4; ++r) {
      float mn = fmaxf(mrow[r], mt[r]);
      alpha[r] = __expf(mrow[r] - mn);
      mrow[r] = mn;
    }
    float p[4][4], ps[4];
    for (int n = 0; n < 4; ++n)
      for (int r = 0; r < 4; ++r) p[n][r] = __expf(sa[n][r] - mrow[r]);
    for (int r = 0; r < 4; ++r) ps[r] = (p[0][r] + p[1][r]) + (p[2][r] + p[3][r]);
    for (int mask = 1; mask < 16; mask <<= 1)
      for (int r = 0; r < 4; ++r) ps[r] += __shfl_xor(ps[r], mask);
    for (int r = 0; r < 4; ++r) lrow[r] = lrow[r] * alpha[r] + ps[r];
    for (int n = 0; n < 4; ++n)
      for (int r = 0; r < 4; ++r) oacc[n][r] *= alpha[r];
    for (int n = 0; n < 4; ++n)
      for (int r = 0; r < 4; ++r)
        Pw[(lg * 4 + r) * LSTR + n * 16 + li] = f2bf(p[n][r]);
    bf16x8 ap[2];
    for (int s = 0; s < 2; ++s)
      ap[s] = *(const bf16x8*)&Pw[li * LSTR + s * 32 + lg * 8];
    for (int n = 0; n < 4; ++n)
      for (int s = 0; s < 2; ++s) {
        bf16x8 bv = *(const bf16x8*)&Vtv[(n * 16 + li) * LSTR + s * 32 + lg * 8];
        oacc[n] = __builtin_amdgcn_mfma_f32_16x16x32_bf16(ap[s], bv, oacc[n], 0, 0, 0);
      }
  }
  for (int r = 0; r < 4; ++r) {
    float inv = 1.0f / lrow[r];
    size_t rowoff = base + (size_t)(q0 + w * 16 + lg * 4 + r) * DH;
    for (int n = 0; n < 4; ++n) Og[rowoff + n * 16 + li] = oacc[n][r] * inv;
  }
}

extern "C" void kernel_launch(void* const* d_in, const int* in_sizes, int n_in,
                              void* d_out, int out_size, void* d_ws, size_t ws_size,
                              hipStream_t stream) {
  const float* Qg = (const float*)d_in[0];
  const float* Kg = (const float*)d_in[1];
  const float* Vg = (const float*)d_in[2];
  float* Og = (float*)d_out;
  if (ws_size >= WS_NEEDED) {
    ushort_t* Kws = (ushort_t*)d_ws;
    ushort_t* Vws = Kws + (size_t)NH * HEAD_WS;
    prep_kv<<<dim3(NT, NH), 256, 0, stream>>>(Kg, Vg, Kws, Vws);
    sdpa_fwd6<<<dim3(1024), 256, 0, stream>>>(Qg, Kws, Vws, Og);
  } else {
    sdpa_fwd_v1<<<dim3(S_LEN / 64, NH), 256, 0, stream>>>(Qg, Kg, Vg, Og);
  }
}

// Round 7
// 98.002 us; speedup vs baseline: 1.6854x; 1.1569x over previous
//
#include <hip/hip_runtime.h>

typedef __bf16 bf16x8 __attribute__((ext_vector_type(8)));
typedef float f32x16 __attribute__((ext_vector_type(16)));
typedef float f32x2 __attribute__((ext_vector_type(2)));
typedef unsigned short ushort_t;
typedef unsigned int uint_t;

#define S_LEN 2048
#define DH    64
#define NH    64                      // N*H = 8*8 heads
#define KB    64
#define NT    (S_LEN / KB)            // 32 kv tiles
#define QB    128
#define TILE_ELEMS (KB * DH)          // 4096 bf16 per packed tile (8 KB)
#define HEAD_WS    (NT * TILE_ELEMS)  // elems per head per tensor
#define WS_NEEDED  (2ull * NH * HEAD_WS * 2ull)  // bytes

#define QSCALE 0.18033688011112043f   // (1/8) * log2(e)

#if __has_builtin(__builtin_amdgcn_exp2f)
#define EXP2(x) __builtin_amdgcn_exp2f(x)
#else
#define EXP2(x) __expf((x) * 0.6931471805599453f)
#endif

static __device__ __forceinline__ unsigned int f32u(float f) {
  union { float f; unsigned int u; } x; x.f = f; return x.u;
}
// bf16 RNE
static __device__ __forceinline__ ushort_t f2bf(float f) {
  unsigned int u = f32u(f);
  return (ushort_t)((u + 0x7FFFu + ((u >> 16) & 1u)) >> 16);
}

static __device__ __forceinline__ void gl_lds16(const ushort_t* g, ushort_t* l) {
  auto gp = reinterpret_cast<const __attribute__((address_space(1))) char*>(
      reinterpret_cast<uintptr_t>(g));
  auto lp = reinterpret_cast<__attribute__((address_space(3))) char*>(
      (unsigned int)reinterpret_cast<uintptr_t>(l));
  __builtin_amdgcn_global_load_lds(gp, lp, 16, 0, 0);  // dst = lp + lane*16
}

// ---------------- prep: K -> bf16 packed+swizzled, V -> bf16 transposed packed+swizzled ----
// packed tile layout: elem (row, col) at byte  row*128 + (((col>>3) ^ (row&7))<<4) + (col&7)*2
__global__ __launch_bounds__(256) void prep_kv(
    const float* __restrict__ Kg, const float* __restrict__ Vg,
    ushort_t* __restrict__ Kws, ushort_t* __restrict__ Vws) {
  __shared__ float Vl[DH * 65];
  const int tid = threadIdx.x;
  const int tile = blockIdx.x, head = blockIdx.y;
  const size_t gbase = ((size_t)head * S_LEN + (size_t)tile * KB) * DH;
  ushort_t* kdst = Kws + ((size_t)head * NT + tile) * TILE_ELEMS;
  ushort_t* vdst = Vws + ((size_t)head * NT + tile) * TILE_ELEMS;

#pragma unroll
  for (int i = 0; i < 4; ++i) {
    int idx = tid + i * 256;
    int row = idx >> 4;            // kv row
    int c0  = (idx & 15) * 4;      // channel start
    float4 kd = *(const float4*)(Kg + gbase + row * DH + c0);
    float4 vd = *(const float4*)(Vg + gbase + row * DH + c0);
    int chunk = (c0 >> 3) ^ (row & 7);
    ushort4 ko;
    ko.x = f2bf(kd.x); ko.y = f2bf(kd.y); ko.z = f2bf(kd.z); ko.w = f2bf(kd.w);
    *(ushort4*)(kdst + row * 64 + chunk * 8 + (c0 & 7)) = ko;
    Vl[(c0 + 0) * 65 + row] = vd.x;
    Vl[(c0 + 1) * 65 + row] = vd.y;
    Vl[(c0 + 2) * 65 + row] = vd.z;
    Vl[(c0 + 3) * 65 + row] = vd.w;
  }
  __syncthreads();
#pragma unroll
  for (int i = 0; i < 4; ++i) {
    int idx = tid + i * 256;
    int c  = idx >> 4;             // channel row of V^T
    int k0 = (idx & 15) * 4;       // kv start
    int chunk = (k0 >> 3) ^ (c & 7);
    ushort4 vo;
    vo.x = f2bf(Vl[c * 65 + k0 + 0]);
    vo.y = f2bf(Vl[c * 65 + k0 + 1]);
    vo.z = f2bf(Vl[c * 65 + k0 + 2]);
    vo.w = f2bf(Vl[c * 65 + k0 + 3]);
    *(ushort4*)(vdst + c * 64 + chunk * 8 + (k0 & 7)) = vo;
  }
}

// ---------------- main: 32x32 MFMA, swapped operands, ring-2, compile-time LDS offsets ----
// S^T = K * Q^T  -> lane holds P^T[kv rows][q = lane&31]
// O^T = V^T * P^T -> lane holds O^T[d rows][q = lane&31]
// Combined LDS: KV[ring][K/V][4096].  From a single per-lane base address:
//   K ring0 = +0, V ring0 = +8192, K ring1 = +16384, V ring1 = +24576 (all ds imm).
__global__ __launch_bounds__(256, 4) void sdpa_fwd7(
    const float* __restrict__ Qg, const ushort_t* __restrict__ Kws,
    const ushort_t* __restrict__ Vws, float* __restrict__ Og) {
  __shared__ __align__(16) ushort_t KV[2][2][TILE_ELEMS];   // 32 KB

  const int tid  = threadIdx.x;
  const int w    = tid >> 6;
  const int lane = tid & 63;
  const int hi   = lane >> 5;
  const int l31  = lane & 31;
  const int bid  = blockIdx.x;
  // XCD-affinity: xcd = bid%8 == head%8
  const int head  = (bid & 7) | ((bid >> 7) << 3);
  const int qtile = (bid >> 3) & 15;
  const int q0    = qtile * QB;
  const size_t base = (size_t)head * S_LEN * DH;
  const ushort_t* ksrc = Kws + (size_t)head * HEAD_WS;
  const ushort_t* vsrc = Vws + (size_t)head * HEAD_WS;

  // ---- Q B-frags: lane supplies Q[q = l31][c = ks*16 + hi*8 + j], pre-scaled ----
  bf16x8 qf[4];
  {
    const float* qp = Qg + base + (size_t)(q0 + w * 32 + l31) * DH;
#pragma unroll
    for (int ks = 0; ks < 4; ++ks) {
      const float* p = qp + ks * 16 + hi * 8;
      float4 f0 = *(const float4*)p;
      float4 f1 = *(const float4*)(p + 4);
      union { ushort_t u[8]; bf16x8 v; } t;
      t.u[0] = f2bf(f0.x * QSCALE); t.u[1] = f2bf(f0.y * QSCALE);
      t.u[2] = f2bf(f0.z * QSCALE); t.u[3] = f2bf(f0.w * QSCALE);
      t.u[4] = f2bf(f1.x * QSCALE); t.u[5] = f2bf(f1.y * QSCALE);
      t.u[6] = f2bf(f1.z * QSCALE); t.u[7] = f2bf(f1.w * QSCALE);
      qf[ks] = t.v;
    }
  }

  // ---- per-lane base addresses into KV[0][0] (8 VGPR, computed once) ----
  // frag (mt, ks): row = mt*32 + l31, chunk = (ks*2 + hi) ^ (row&7); byte = row*128 + chunk*16
  const char* A[2][4];
  {
    const int r7 = l31 & 7;
    const char* kvb = (const char*)&KV[0][0][0];
#pragma unroll
    for (int mt = 0; mt < 2; ++mt)
#pragma unroll
      for (int ks = 0; ks < 4; ++ks)
        A[mt][ks] = kvb + (mt * 32 + l31) * 128 + ((((ks << 1) | hi) ^ r7) << 4);
  }

  // persistent zero C-operand (kills 32 v_movs/tile of accumulator zero-init)
  f32x16 Z16;
#pragma unroll
  for (int r = 0; r < 16; ++r) Z16[r] = 0.f;

  f32x16 oacc0, oacc1;
#pragma unroll
  for (int r = 0; r < 16; ++r) { oacc0[r] = 0.f; oacc1[r] = 0.f; }
  f32x2 ls0 = {0.f, 0.f}, ls1 = {0.f, 0.f};

#define STAGE(tt, bb) do { \
    const ushort_t* ks_ = ksrc + (tt) * TILE_ELEMS + w * 512 + lane * 8; \
    const ushort_t* vs_ = vsrc + (tt) * TILE_ELEMS + w * 512 + lane * 8; \
    gl_lds16(ks_,        &KV[bb][0][w * 512]); \
    gl_lds16(ks_ + 2048, &KV[bb][0][2048 + w * 512]); \
    gl_lds16(vs_,        &KV[bb][1][w * 512]); \
    gl_lds16(vs_ + 2048, &KV[bb][1][2048 + w * 512]); \
  } while (0)

  // TOFF: 0 = ring buf 0, 16384 = ring buf 1 (V at +8192 within each).
#define COMPUTE(TOFF) do { \
    bf16x8 ka0[4], ka1[4]; \
    _Pragma("unroll") for (int ks = 0; ks < 4; ++ks) { \
      ka0[ks] = *(const bf16x8*)(A[0][ks] + (TOFF)); \
      ka1[ks] = *(const bf16x8*)(A[1][ks] + (TOFF)); } \
    f32x16 sa0, sa1; \
    __builtin_amdgcn_s_setprio(1); \
    sa0 = __builtin_amdgcn_mfma_f32_32x32x16_bf16(ka0[0], qf[0], Z16, 0, 0, 0); \
    sa1 = __builtin_amdgcn_mfma_f32_32x32x16_bf16(ka1[0], qf[0], Z16, 0, 0, 0); \
    _Pragma("unroll") for (int ks = 1; ks < 4; ++ks) { \
      sa0 = __builtin_amdgcn_mfma_f32_32x32x16_bf16(ka0[ks], qf[ks], sa0, 0, 0, 0); \
      sa1 = __builtin_amdgcn_mfma_f32_32x32x16_bf16(ka1[ks], qf[ks], sa1, 0, 0, 0); } \
    __builtin_amdgcn_s_setprio(0); \
    union { uint_t u[16]; bf16x8 v[4]; } P; \
    _Pragma("unroll") for (int i = 0; i < 8; ++i) { \
      float a = EXP2(sa0[2 * i]), b = EXP2(sa0[2 * i + 1]); \
      ls0 += (f32x2){a, b}; \
      asm("v_cvt_pk_bf16_f32 %0, %1, %2" : "=v"(P.u[i]) : "v"(a), "v"(b)); } \
    _Pragma("unroll") for (int i = 0; i < 8; ++i) { \
      float a = EXP2(sa1[2 * i]), b = EXP2(sa1[2 * i + 1]); \
      ls1 += (f32x2){a, b}; \
      asm("v_cvt_pk_bf16_f32 %0, %1, %2" : "=v"(P.u[i + 8]) : "v"(a), "v"(b)); } \
    _Pragma("unroll") for (int g = 0; g < 4; ++g) { \
      asm("v_permlane32_swap_b32 %0, %1" : "+v"(P.u[4 * g + 0]), "+v"(P.u[4 * g + 2])); \
      asm("v_permlane32_swap_b32 %0, %1" : "+v"(P.u[4 * g + 1]), "+v"(P.u[4 * g + 3])); } \
    __builtin_amdgcn_s_setprio(1); \
    { bf16x8 vv; \
      vv = *(const bf16x8*)(A[0][0] + (TOFF) + 8192); \
      oacc0 = __builtin_amdgcn_mfma_f32_32x32x16_bf16(vv, P.v[0], oacc0, 0, 0, 0); \
      vv = *(const bf16x8*)(A[1][0] + (TOFF) + 8192); \
      oacc1 = __builtin_amdgcn_mfma_f32_32x32x16_bf16(vv, P.v[0], oacc1, 0, 0, 0); \
      vv = *(const bf16x8*)(A[0][1] + (TOFF) + 8192); \
      oacc0 = __builtin_amdgcn_mfma_f32_32x32x16_bf16(vv, P.v[1], oacc0, 0, 0, 0); \
      vv = *(const bf16x8*)(A[1][1] + (TOFF) + 8192); \
      oacc1 = __builtin_amdgcn_mfma_f32_32x32x16_bf16(vv, P.v[1], oacc1, 0, 0, 0); \
      vv = *(const bf16x8*)(A[0][2] + (TOFF) + 8192); \
      oacc0 = __builtin_amdgcn_mfma_f32_32x32x16_bf16(vv, P.v[2], oacc0, 0, 0, 0); \
      vv = *(const bf16x8*)(A[1][2] + (TOFF) + 8192); \
      oacc1 = __builtin_amdgcn_mfma_f32_32x32x16_bf16(vv, P.v[2], oacc1, 0, 0, 0); \
      vv = *(const bf16x8*)(A[0][3] + (TOFF) + 8192); \
      oacc0 = __builtin_amdgcn_mfma_f32_32x32x16_bf16(vv, P.v[3], oacc0, 0, 0, 0); \
      vv = *(const bf16x8*)(A[1][3] + (TOFF) + 8192); \
      oacc1 = __builtin_amdgcn_mfma_f32_32x32x16_bf16(vv, P.v[3], oacc1, 0, 0, 0); } \
    __builtin_amdgcn_s_setprio(0); \
  } while (0)

  // prologue: stage tile 0 into ring buf 0
  STAGE(0, 0);
  __syncthreads();

#pragma unroll 1
  for (int t = 0; t < NT; t += 2) {
    if (t + 1 < NT) STAGE(t + 1, 1);   // prefetch into buf 1, overlaps compute below
    COMPUTE(0);                        // compute tile t from buf 0
    __syncthreads();                   // buf1 DMA visible; buf0 free
    if (t + 2 < NT) STAGE(t + 2, 0);
    COMPUTE(16384);                    // compute tile t+1 from buf 1
    __syncthreads();
  }
#undef STAGE
#undef COMPUTE

  // ---- epilogue: l is lane-local (q = l31); O^T regs -> row-major O with float4 ----
  float lsum = ls0.x + ls0.y + ls1.x + ls1.y;
  float ltot = lsum + __shfl_xor(lsum, 32);
  float linv = 1.0f / ltot;
  float* orow = Og + base + (size_t)(q0 + w * 32 + l31) * DH;
#pragma unroll
  for (int rr = 0; rr < 4; ++rr) {
    float4 o0, o1;
    o0.x = oacc0[4 * rr + 0] * linv; o0.y = oacc0[4 * rr + 1] * linv;
    o0.z = oacc0[4 * rr + 2] * linv; o0.w = oacc0[4 * rr + 3] * linv;
    o1.x = oacc1[4 * rr + 0] * linv; o1.y = oacc1[4 * rr + 1] * linv;
    o1.z = oacc1[4 * rr + 2] * linv; o1.w = oacc1[4 * rr + 3] * linv;
    *(float4*)(orow + 8 * rr + 4 * hi) = o0;          // d = 0..31 tile
    *(float4*)(orow + 32 + 8 * rr + 4 * hi) = o1;     // d = 32..63 tile
  }
}

// ---------------- fallback (used only if ws too small): self-contained fp32->bf16 ----
#define LSTR 72
__global__ __launch_bounds__(256) void sdpa_fwd_v1(
    const float* __restrict__ Qg, const float* __restrict__ Kg,
    const float* __restrict__ Vg, float* __restrict__ Og) {
  __shared__ __align__(16) ushort_t Klv[KB * LSTR];
  __shared__ __align__(16) ushort_t Vtv[DH * LSTR];
  __shared__ __align__(16) ushort_t Plv[4 * 16 * LSTR];
  typedef float f32x4s __attribute__((ext_vector_type(4)));
  const int tid = threadIdx.x;
  const int w = tid >> 6, lane = tid & 63, lg = lane >> 4, li = lane & 15;
  const int bh = blockIdx.y;
  const int q0 = blockIdx.x * 64;
  const size_t base = (size_t)bh * S_LEN * DH;
  bf16x8 aq[2];
  {
    const float* qrow = Qg + base + (size_t)(q0 + w * 16 + li) * DH;
    for (int s = 0; s < 2; ++s) {
      union { ushort_t u[8]; bf16x8 v; } t;
      const float* p = qrow + s * 32 + lg * 8;
      float4 f0 = *(const float4*)(p);
      float4 f1 = *(const float4*)(p + 4);
      t.u[0] = f2bf(f0.x * 0.125f); t.u[1] = f2bf(f0.y * 0.125f);
      t.u[2] = f2bf(f0.z * 0.125f); t.u[3] = f2bf(f0.w * 0.125f);
      t.u[4] = f2bf(f1.x * 0.125f); t.u[5] = f2bf(f1.y * 0.125f);
      t.u[6] = f2bf(f1.z * 0.125f); t.u[7] = f2bf(f1.w * 0.125f);
      aq[s] = t.v;
    }
  }
  f32x4s oacc[4]; float mrow[4], lrow[4];
  for (int n = 0; n < 4; ++n) oacc[n] = (f32x4s){0.f, 0.f, 0.f, 0.f};
  for (int r = 0; r < 4; ++r) { mrow[r] = -1e30f; lrow[r] = 0.f; }
  ushort_t* Pw = &Plv[w * 16 * LSTR];
  for (int kv0 = 0; kv0 < S_LEN; kv0 += KB) {
    __syncthreads();
    for (int i = 0; i < 4; ++i) {
      int f4 = tid + i * 256;
      int row = f4 >> 4, c0 = (f4 & 15) * 4;
      size_t goff = base + (size_t)(kv0 + row) * DH + c0;
      float4 kd = *(const float4*)(Kg + goff);
      float4 vd = *(const float4*)(Vg + goff);
      ushort_t* kp = &Klv[row * LSTR + c0];
      kp[0] = f2bf(kd.x); kp[1] = f2bf(kd.y); kp[2] = f2bf(kd.z); kp[3] = f2bf(kd.w);
      Vtv[(c0 + 0) * LSTR + row] = f2bf(vd.x);
      Vtv[(c0 + 1) * LSTR + row] = f2bf(vd.y);
      Vtv[(c0 + 2) * LSTR + row] = f2bf(vd.z);
      Vtv[(c0 + 3) * LSTR + row] = f2bf(vd.w);
    }
    __syncthreads();
    f32x4s sa[4];
    for (int n = 0; n < 4; ++n) sa[n] = (f32x4s){0.f, 0.f, 0.f, 0.f};
    for (int n = 0; n < 4; ++n)
      for (int s = 0; s < 2; ++s) {
        bf16x8 bk = *(const bf16x8*)&Klv[(n * 16 + li) * LSTR + s * 32 + lg * 8];
        sa[n] = __builtin_amdgcn_mfma_f32_16x16x32_bf16(aq[s], bk, sa[n], 0, 0, 0);
      }
    float mt[4];
    for (int r = 0; r < 4; ++r)
      mt[r] = fmaxf(fmaxf(sa[0][r], sa[1][r]), fmaxf(sa[2][r], sa[3][r]));
    for (int mask = 1; mask < 16; mask <<= 1)
      for (int r = 0; r < 4; ++r) mt[r] = fmaxf(mt[r], __shfl_xor(mt[r], mask));
    float alpha[4];
    for (int r = 0; r < 4; ++r) {
      float mn = fmaxf(mrow[r], mt[r]);
      alpha[r] = __expf(mrow[r] - mn);
      mrow[r] = mn;
    }
    float p[4][4], ps[4];
    for (int n = 0; n < 4; ++n)
      for (int r = 0; r < 4; ++r) p[n][r] = __expf(sa[n][r] - mrow[r]);
    for (int r = 0; r < 4; ++r) ps[r] = (p[0][r] + p[1][r]) + (p[2][r] + p[3][r]);
    for (int mask = 1; mask < 16; mask <<= 1)
      for (int r = 0; r < 4; ++r) ps[r] += __shfl_xor(ps[r], mask);
    for (int r = 0; r < 4; ++r) lrow[r] = lrow[r] * alpha[r] + ps[r];
    for (int n = 0; n < 4; ++n)
      for (int r = 0; r < 4; ++r) oacc[n][r] *= alpha[r];
    for (int n = 0; n < 4; ++n)
      for (int r = 0; r < 4; ++r)
        Pw[(lg * 4 + r) * LSTR + n * 16 + li] = f2bf(p[n][r]);
    bf16x8 ap[2];
    for (int s = 0; s < 2; ++s)
      ap[s] = *(const bf16x8*)&Pw[li * LSTR + s * 32 + lg * 8];
    for (int n = 0; n < 4; ++n)
      for (int s = 0; s < 2; ++s) {
        bf16x8 bv = *(const bf16x8*)&Vtv[(n * 16 + li) * LSTR + s * 32 + lg * 8];
        oacc[n] = __builtin_amdgcn_mfma_f32_16x16x32_bf16(ap[s], bv, oacc[n], 0, 0, 0);
      }
  }
  for (int r = 0; r < 4; ++r) {
    float inv = 1.0f / lrow[r];
    size_t rowoff = base + (size_t)(q0 + w * 16 + lg * 4 + r) * DH;
    for (int n = 0; n < 4; ++n) Og[rowoff + n * 16 + li] = oacc[n][r] * inv;
  }
}

extern "C" void kernel_launch(void* const* d_in, const int* in_sizes, int n_in,
                              void* d_out, int out_size, void* d_ws, size_t ws_size,
                              hipStream_t stream) {
  const float* Qg = (const float*)d_in[0];
  const float* Kg = (const float*)d_in[1];
  const float* Vg = (const float*)d_in[2];
  float* Og = (float*)d_out;
  if (ws_size >= WS_NEEDED) {
    ushort_t* Kws = (ushort_t*)d_ws;
    ushort_t* Vws = Kws + (size_t)NH * HEAD_WS;
    prep_kv<<<dim3(NT, NH), 256, 0, stream>>>(Kg, Vg, Kws, Vws);
    sdpa_fwd7<<<dim3(1024), 256, 0, stream>>>(Qg, Kws, Vws, Og);
  } else {
    sdpa_fwd_v1<<<dim3(S_LEN / 64, NH), 256, 0, stream>>>(Qg, Kg, Vg, Og);
  }
}

// Round 12
// 97.876 us; speedup vs baseline: 1.6876x; 1.0013x over previous
//
#include <hip/hip_runtime.h>

typedef __bf16 bf16x8 __attribute__((ext_vector_type(8)));
typedef float f32x16 __attribute__((ext_vector_type(16)));
typedef float f32x2 __attribute__((ext_vector_type(2)));
typedef unsigned short ushort_t;
typedef unsigned int uint_t;

#define S_LEN 2048
#define DH    64
#define NH    64                      // N*H = 8*8 heads
#define KB    64
#define NT    (S_LEN / KB)            // 32 kv tiles
#define QB    128
#define TILE_ELEMS (KB * DH)          // 4096 bf16 per packed tile (8 KB)
#define HEAD_WS    (NT * TILE_ELEMS)  // elems per head per tensor
#define WS_NEEDED  (2ull * NH * HEAD_WS * 2ull)  // bytes

#define QSCALE 0.18033688011112043f   // (1/8) * log2(e)

#if __has_builtin(__builtin_amdgcn_exp2f)
#define EXP2(x) __builtin_amdgcn_exp2f(x)
#else
#define EXP2(x) __expf((x) * 0.6931471805599453f)
#endif

static __device__ __forceinline__ unsigned int f32u(float f) {
  union { float f; unsigned int u; } x; x.f = f; return x.u;
}
// bf16 RNE
static __device__ __forceinline__ ushort_t f2bf(float f) {
  unsigned int u = f32u(f);
  return (ushort_t)((u + 0x7FFFu + ((u >> 16) & 1u)) >> 16);
}

static __device__ __forceinline__ void gl_lds16(const ushort_t* g, ushort_t* l) {
  auto gp = reinterpret_cast<const __attribute__((address_space(1))) char*>(
      reinterpret_cast<uintptr_t>(g));
  auto lp = reinterpret_cast<__attribute__((address_space(3))) char*>(
      (unsigned int)reinterpret_cast<uintptr_t>(l));
  __builtin_amdgcn_global_load_lds(gp, lp, 16, 0, 0);  // dst = lp + lane*16
}

// ---------------- prep: K -> bf16 packed+swizzled, V -> bf16 transposed packed+swizzled ----
// packed tile layout: elem (row, col) at byte  row*128 + (((col>>3) ^ (row&7))<<4) + (col&7)*2
__global__ __launch_bounds__(256) void prep_kv(
    const float* __restrict__ Kg, const float* __restrict__ Vg,
    ushort_t* __restrict__ Kws, ushort_t* __restrict__ Vws) {
  __shared__ float Vl[DH * 65];
  const int tid = threadIdx.x;
  const int tile = blockIdx.x, head = blockIdx.y;
  const size_t gbase = ((size_t)head * S_LEN + (size_t)tile * KB) * DH;
  ushort_t* kdst = Kws + ((size_t)head * NT + tile) * TILE_ELEMS;
  ushort_t* vdst = Vws + ((size_t)head * NT + tile) * TILE_ELEMS;

#pragma unroll
  for (int i = 0; i < 4; ++i) {
    int idx = tid + i * 256;
    int row = idx >> 4;            // kv row
    int c0  = (idx & 15) * 4;      // channel start
    float4 kd = *(const float4*)(Kg + gbase + row * DH + c0);
    float4 vd = *(const float4*)(Vg + gbase + row * DH + c0);
    int chunk = (c0 >> 3) ^ (row & 7);
    ushort4 ko;
    ko.x = f2bf(kd.x); ko.y = f2bf(kd.y); ko.z = f2bf(kd.z); ko.w = f2bf(kd.w);
    *(ushort4*)(kdst + row * 64 + chunk * 8 + (c0 & 7)) = ko;
    Vl[(c0 + 0) * 65 + row] = vd.x;
    Vl[(c0 + 1) * 65 + row] = vd.y;
    Vl[(c0 + 2) * 65 + row] = vd.z;
    Vl[(c0 + 3) * 65 + row] = vd.w;
  }
  __syncthreads();
#pragma unroll
  for (int i = 0; i < 4; ++i) {
    int idx = tid + i * 256;
    int c  = idx >> 4;             // channel row of V^T
    int k0 = (idx & 15) * 4;       // kv start
    int chunk = (k0 >> 3) ^ (c & 7);
    ushort4 vo;
    vo.x = f2bf(Vl[c * 65 + k0 + 0]);
    vo.y = f2bf(Vl[c * 65 + k0 + 1]);
    vo.z = f2bf(Vl[c * 65 + k0 + 2]);
    vo.w = f2bf(Vl[c * 65 + k0 + 3]);
    *(ushort4*)(vdst + c * 64 + chunk * 8 + (k0 & 7)) = vo;
  }
}

// ---------------- main: 32x32 MFMA, swapped operands, ring-2, compile-time LDS offsets ----
// Byte-exact re-lock of the round-7 verified kernel (98.0 us total, passed).
// S^T = K * Q^T  -> lane holds P^T[kv rows][q = lane&31]
// O^T = V^T * P^T -> lane holds O^T[d rows][q = lane&31]
// Combined LDS: KV[ring][K/V][4096].  From a single per-lane base address:
//   K ring0 = +0, V ring0 = +8192, K ring1 = +16384, V ring1 = +24576 (all ds imm).
__global__ __launch_bounds__(256, 4) void sdpa_fwd7(
    const float* __restrict__ Qg, const ushort_t* __restrict__ Kws,
    const ushort_t* __restrict__ Vws, float* __restrict__ Og) {
  __shared__ __align__(16) ushort_t KV[2][2][TILE_ELEMS];   // 32 KB

  const int tid  = threadIdx.x;
  const int w    = tid >> 6;
  const int lane = tid & 63;
  const int hi   = lane >> 5;
  const int l31  = lane & 31;
  const int bid  = blockIdx.x;
  // XCD-affinity: xcd = bid%8 == head%8
  const int head  = (bid & 7) | ((bid >> 7) << 3);
  const int qtile = (bid >> 3) & 15;
  const int q0    = qtile * QB;
  const size_t base = (size_t)head * S_LEN * DH;
  const ushort_t* ksrc = Kws + (size_t)head * HEAD_WS;
  const ushort_t* vsrc = Vws + (size_t)head * HEAD_WS;

  // ---- Q B-frags: lane supplies Q[q = l31][c = ks*16 + hi*8 + j], pre-scaled ----
  bf16x8 qf[4];
  {
    const float* qp = Qg + base + (size_t)(q0 + w * 32 + l31) * DH;
#pragma unroll
    for (int ks = 0; ks < 4; ++ks) {
      const float* p = qp + ks * 16 + hi * 8;
      float4 f0 = *(const float4*)p;
      float4 f1 = *(const float4*)(p + 4);
      union { ushort_t u[8]; bf16x8 v; } t;
      t.u[0] = f2bf(f0.x * QSCALE); t.u[1] = f2bf(f0.y * QSCALE);
      t.u[2] = f2bf(f0.z * QSCALE); t.u[3] = f2bf(f0.w * QSCALE);
      t.u[4] = f2bf(f1.x * QSCALE); t.u[5] = f2bf(f1.y * QSCALE);
      t.u[6] = f2bf(f1.z * QSCALE); t.u[7] = f2bf(f1.w * QSCALE);
      qf[ks] = t.v;
    }
  }

  // ---- per-lane base addresses into KV[0][0] (8 VGPR, computed once) ----
  // frag (mt, ks): row = mt*32 + l31, chunk = (ks*2 + hi) ^ (row&7); byte = row*128 + chunk*16
  const char* A[2][4];
  {
    const int r7 = l31 & 7;
    const char* kvb = (const char*)&KV[0][0][0];
#pragma unroll
    for (int mt = 0; mt < 2; ++mt)
#pragma unroll
      for (int ks = 0; ks < 4; ++ks)
        A[mt][ks] = kvb + (mt * 32 + l31) * 128 + ((((ks << 1) | hi) ^ r7) << 4);
  }

  // persistent zero C-operand (kills 32 v_movs/tile of accumulator zero-init)
  f32x16 Z16;
#pragma unroll
  for (int r = 0; r < 16; ++r) Z16[r] = 0.f;

  f32x16 oacc0, oacc1;
#pragma unroll
  for (int r = 0; r < 16; ++r) { oacc0[r] = 0.f; oacc1[r] = 0.f; }
  f32x2 ls0 = {0.f, 0.f}, ls1 = {0.f, 0.f};

#define STAGE(tt, bb) do { \
    const ushort_t* ks_ = ksrc + (tt) * TILE_ELEMS + w * 512 + lane * 8; \
    const ushort_t* vs_ = vsrc + (tt) * TILE_ELEMS + w * 512 + lane * 8; \
    gl_lds16(ks_,        &KV[bb][0][w * 512]); \
    gl_lds16(ks_ + 2048, &KV[bb][0][2048 + w * 512]); \
    gl_lds16(vs_,        &KV[bb][1][w * 512]); \
    gl_lds16(vs_ + 2048, &KV[bb][1][2048 + w * 512]); \
  } while (0)

  // TOFF: 0 = ring buf 0, 16384 = ring buf 1 (V at +8192 within each).
#define COMPUTE(TOFF) do { \
    bf16x8 ka0[4], ka1[4]; \
    _Pragma("unroll") for (int ks = 0; ks < 4; ++ks) { \
      ka0[ks] = *(const bf16x8*)(A[0][ks] + (TOFF)); \
      ka1[ks] = *(const bf16x8*)(A[1][ks] + (TOFF)); } \
    f32x16 sa0, sa1; \
    __builtin_amdgcn_s_setprio(1); \
    sa0 = __builtin_amdgcn_mfma_f32_32x32x16_bf16(ka0[0], qf[0], Z16, 0, 0, 0); \
    sa1 = __builtin_amdgcn_mfma_f32_32x32x16_bf16(ka1[0], qf[0], Z16, 0, 0, 0); \
    _Pragma("unroll") for (int ks = 1; ks < 4; ++ks) { \
      sa0 = __builtin_amdgcn_mfma_f32_32x32x16_bf16(ka0[ks], qf[ks], sa0, 0, 0, 0); \
      sa1 = __builtin_amdgcn_mfma_f32_32x32x16_bf16(ka1[ks], qf[ks], sa1, 0, 0, 0); } \
    __builtin_amdgcn_s_setprio(0); \
    union { uint_t u[16]; bf16x8 v[4]; } P; \
    _Pragma("unroll") for (int i = 0; i < 8; ++i) { \
      float a = EXP2(sa0[2 * i]), b = EXP2(sa0[2 * i + 1]); \
      ls0 += (f32x2){a, b}; \
      asm("v_cvt_pk_bf16_f32 %0, %1, %2" : "=v"(P.u[i]) : "v"(a), "v"(b)); } \
    _Pragma("unroll") for (int i = 0; i < 8; ++i) { \
      float a = EXP2(sa1[2 * i]), b = EXP2(sa1[2 * i + 1]); \
      ls1 += (f32x2){a, b}; \
      asm("v_cvt_pk_bf16_f32 %0, %1, %2" : "=v"(P.u[i + 8]) : "v"(a), "v"(b)); } \
    _Pragma("unroll") for (int g = 0; g < 4; ++g) { \
      asm("v_permlane32_swap_b32 %0, %1" : "+v"(P.u[4 * g + 0]), "+v"(P.u[4 * g + 2])); \
      asm("v_permlane32_swap_b32 %0, %1" : "+v"(P.u[4 * g + 1]), "+v"(P.u[4 * g + 3])); } \
    __builtin_amdgcn_s_setprio(1); \
    { bf16x8 vv; \
      vv = *(const bf16x8*)(A[0][0] + (TOFF) + 8192); \
      oacc0 = __builtin_amdgcn_mfma_f32_32x32x16_bf16(vv, P.v[0], oacc0, 0, 0, 0); \
      vv = *(const bf16x8*)(A[1][0] + (TOFF) + 8192); \
      oacc1 = __builtin_amdgcn_mfma_f32_32x32x16_bf16(vv, P.v[0], oacc1, 0, 0, 0); \
      vv = *(const bf16x8*)(A[0][1] + (TOFF) + 8192); \
      oacc0 = __builtin_amdgcn_mfma_f32_32x32x16_bf16(vv, P.v[1], oacc0, 0, 0, 0); \
      vv = *(const bf16x8*)(A[1][1] + (TOFF) + 8192); \
      oacc1 = __builtin_amdgcn_mfma_f32_32x32x16_bf16(vv, P.v[1], oacc1, 0, 0, 0); \
      vv = *(const bf16x8*)(A[0][2] + (TOFF) + 8192); \
      oacc0 = __builtin_amdgcn_mfma_f32_32x32x16_bf16(vv, P.v[2], oacc0, 0, 0, 0); \
      vv = *(const bf16x8*)(A[1][2] + (TOFF) + 8192); \
      oacc1 = __builtin_amdgcn_mfma_f32_32x32x16_bf16(vv, P.v[2], oacc1, 0, 0, 0); \
      vv = *(const bf16x8*)(A[0][3] + (TOFF) + 8192); \
      oacc0 = __builtin_amdgcn_mfma_f32_32x32x16_bf16(vv, P.v[3], oacc0, 0, 0, 0); \
      vv = *(const bf16x8*)(A[1][3] + (TOFF) + 8192); \
      oacc1 = __builtin_amdgcn_mfma_f32_32x32x16_bf16(vv, P.v[3], oacc1, 0, 0, 0); } \
    __builtin_amdgcn_s_setprio(0); \
  } while (0)

  // prologue: stage tile 0 into ring buf 0
  STAGE(0, 0);
  __syncthreads();

#pragma unroll 1
  for (int t = 0; t < NT; t += 2) {
    if (t + 1 < NT) STAGE(t + 1, 1);   // prefetch into buf 1, overlaps compute below
    COMPUTE(0);                        // compute tile t from buf 0
    __syncthreads();                   // buf1 DMA visible; buf0 free
    if (t + 2 < NT) STAGE(t + 2, 0);
    COMPUTE(16384);                    // compute tile t+1 from buf 1
    __syncthreads();
  }
#undef STAGE
#undef COMPUTE

  // ---- epilogue: l is lane-local (q = l31); O^T regs -> row-major O with float4 ----
  float lsum = ls0.x + ls0.y + ls1.x + ls1.y;
  float ltot = lsum + __shfl_xor(lsum, 32);
  float linv = 1.0f / ltot;
  float* orow = Og + base + (size_t)(q0 + w * 32 + l31) * DH;
#pragma unroll
  for (int rr = 0; rr < 4; ++rr) {
    float4 o0, o1;
    o0.x = oacc0[4 * rr + 0] * linv; o0.y = oacc0[4 * rr + 1] * linv;
    o0.z = oacc0[4 * rr + 2] * linv; o0.w = oacc0[4 * rr + 3] * linv;
    o1.x = oacc1[4 * rr + 0] * linv; o1.y = oacc1[4 * rr + 1] * linv;
    o1.z = oacc1[4 * rr + 2] * linv; o1.w = oacc1[4 * rr + 3] * linv;
    *(float4*)(orow + 8 * rr + 4 * hi) = o0;          // d = 0..31 tile
    *(float4*)(orow + 32 + 8 * rr + 4 * hi) = o1;     // d = 32..63 tile
  }
}

// ---------------- fallback (used only if ws too small): self-contained fp32->bf16 ----
#define LSTR 72
__global__ __launch_bounds__(256) void sdpa_fwd_v1(
    const float* __restrict__ Qg, const float* __restrict__ Kg,
    const float* __restrict__ Vg, float* __restrict__ Og) {
  __shared__ __align__(16) ushort_t Klv[KB * LSTR];
  __shared__ __align__(16) ushort_t Vtv[DH * LSTR];
  __shared__ __align__(16) ushort_t Plv[4 * 16 * LSTR];
  typedef float f32x4s __attribute__((ext_vector_type(4)));
  const int tid = threadIdx.x;
  const int w = tid >> 6, lane = tid & 63, lg = lane >> 4, li = lane & 15;
  const int bh = blockIdx.y;
  const int q0 = blockIdx.x * 64;
  const size_t base = (size_t)bh * S_LEN * DH;
  bf16x8 aq[2];
  {
    const float* qrow = Qg + base + (size_t)(q0 + w * 16 + li) * DH;
    for (int s = 0; s < 2; ++s) {
      union { ushort_t u[8]; bf16x8 v; } t;
      const float* p = qrow + s * 32 + lg * 8;
      float4 f0 = *(const float4*)(p);
      float4 f1 = *(const float4*)(p + 4);
      t.u[0] = f2bf(f0.x * 0.125f); t.u[1] = f2bf(f0.y * 0.125f);
      t.u[2] = f2bf(f0.z * 0.125f); t.u[3] = f2bf(f0.w * 0.125f);
      t.u[4] = f2bf(f1.x * 0.125f); t.u[5] = f2bf(f1.y * 0.125f);
      t.u[6] = f2bf(f1.z * 0.125f); t.u[7] = f2bf(f1.w * 0.125f);
      aq[s] = t.v;
    }
  }
  f32x4s oacc[4]; float mrow[4], lrow[4];
  for (int n = 0; n < 4; ++n) oacc[n] = (f32x4s){0.f, 0.f, 0.f, 0.f};
  for (int r = 0; r < 4; ++r) { mrow[r] = -1e30f; lrow[r] = 0.f; }
  ushort_t* Pw = &Plv[w * 16 * LSTR];
  for (int kv0 = 0; kv0 < S_LEN; kv0 += KB) {
    __syncthreads();
    for (int i = 0; i < 4; ++i) {
      int f4 = tid + i * 256;
      int row = f4 >> 4, c0 = (f4 & 15) * 4;
      size_t goff = base + (size_t)(kv0 + row) * DH + c0;
      float4 kd = *(const float4*)(Kg + goff);
      float4 vd = *(const float4*)(Vg + goff);
      ushort_t* kp = &Klv[row * LSTR + c0];
      kp[0] = f2bf(kd.x); kp[1] = f2bf(kd.y); kp[2] = f2bf(kd.z); kp[3] = f2bf(kd.w);
      Vtv[(c0 + 0) * LSTR + row] = f2bf(vd.x);
      Vtv[(c0 + 1) * LSTR + row] = f2bf(vd.y);
      Vtv[(c0 + 2) * LSTR + row] = f2bf(vd.z);
      Vtv[(c0 + 3) * LSTR + row] = f2bf(vd.w);
    }
    __syncthreads();
    f32x4s sa[4];
    for (int n = 0; n < 4; ++n) sa[n] = (f32x4s){0.f, 0.f, 0.f, 0.f};
    for (int n = 0; n < 4; ++n)
      for (int s = 0; s < 2; ++s) {
        bf16x8 bk = *(const bf16x8*)&Klv[(n * 16 + li) * LSTR + s * 32 + lg * 8];
        sa[n] = __builtin_amdgcn_mfma_f32_16x16x32_bf16(aq[s], bk, sa[n], 0, 0, 0);
      }
    float mt[4];
    for (int r = 0; r < 4; ++r)
      mt[r] = fmaxf(fmaxf(sa[0][r], sa[1][r]), fmaxf(sa[2][r], sa[3][r]));
    for (int mask = 1; mask < 16; mask <<= 1)
      for (int r = 0; r < 4; ++r) mt[r] = fmaxf(mt[r], __shfl_xor(mt[r], mask));
    float alpha[4];
    for (int r = 0; r < 4; ++r) {
      float mn = fmaxf(mrow[r], mt[r]);
      alpha[r] = __expf(mrow[r] - mn);
      mrow[r] = mn;
    }
    float p[4][4], ps[4];
    for (int n = 0; n < 4; ++n)
      for (int r = 0; r < 4; ++r) p[n][r] = __expf(sa[n][r] - mrow[r]);
    for (int r = 0; r < 4; ++r) ps[r] = (p[0][r] + p[1][r]) + (p[2][r] + p[3][r]);
    for (int mask = 1; mask < 16; mask <<= 1)
      for (int r = 0; r < 4; ++r) ps[r] += __shfl_xor(ps[r], mask);
    for (int r = 0; r < 4; ++r) lrow[r] = lrow[r] * alpha[r] + ps[r];
    for (int n = 0; n < 4; ++n)
      for (int r = 0; r < 4; ++r) oacc[n][r] *= alpha[r];
    for (int n = 0; n < 4; ++n)
      for (int r = 0; r < 4; ++r)
        Pw[(lg * 4 + r) * LSTR + n * 16 + li] = f2bf(p[n][r]);
    bf16x8 ap[2];
    for (int s = 0; s < 2; ++s)
      ap[s] = *(const bf16x8*)&Pw[li * LSTR + s * 32 + lg * 8];
    for (int n = 0; n < 4; ++n)
      for (int s = 0; s < 2; ++s) {
        bf16x8 bv = *(const bf16x8*)&Vtv[(n * 16 + li) * LSTR + s * 32 + lg * 8];
        oacc[n] = __builtin_amdgcn_mfma_f32_16x16x32_bf16(ap[s], bv, oacc[n], 0, 0, 0);
      }
  }
  for (int r = 0; r < 4; ++r) {
    float inv = 1.0f / lrow[r];
    size_t rowoff = base + (size_t)(q0 + w * 16 + lg * 4 + r) * DH;
    for (int n = 0; n < 4; ++n) Og[rowoff + n * 16 + li] = oacc[n][r] * inv;
  }
}

extern "C" void kernel_launch(void* const* d_in, const int* in_sizes, int n_in,
                              void* d_out, int out_size, void* d_ws, size_t ws_size,
                              hipStream_t stream) {
  const float* Qg = (const float*)d_in[0];
  const float* Kg = (const float*)d_in[1];
  const float* Vg = (const float*)d_in[2];
  float* Og = (float*)d_out;
  if (ws_size >= WS_NEEDED) {
    ushort_t* Kws = (ushort_t*)d_ws;
    ushort_t* Vws = Kws + (size_t)NH * HEAD_WS;
    prep_kv<<<dim3(NT, NH), 256, 0, stream>>>(Kg, Vg, Kws, Vws);
    sdpa_fwd7<<<dim3(1024), 256, 0, stream>>>(Qg, Kws, Vws, Og);
  } else {
    sdpa_fwd_v1<<<dim3(S_LEN / 64, NH), 256, 0, stream>>>(Qg, Kg, Vg, Og);
  }
}